// Round 17
// baseline (102.952 us; speedup 1.0000x reference)
//
#include <hip/hip_runtime.h>
#include <math.h>

#define NX 128
#define NY 128
#define NZ 64
#define NVOX (NX * NY * NZ)   // 1048576 = 1<<20
#define NC 32
#define FH 120
#define FW 160
#define FHW (FH * FW)         // 19200
#define VOXSZ 0.04f
#define NB 2
#define T_BYTES ((size_t)NB * FHW * NC * 4)   // 4,915,200

typedef float f32x4 __attribute__((ext_vector_type(4)));

// Transpose features (B,C,H*W) -> T (B, H*W, C).
__global__ __launch_bounds__(256) void transpose_feat_kernel(
    const float* __restrict__ feat, float* __restrict__ T)
{
    const int t = blockIdx.x * 256 + threadIdx.x;     // 0..38399
    const int b = t / FHW;
    const int pix = t - b * FHW;
    const float* fb = feat + (size_t)b * NC * FHW + pix;
    float v[NC];
    #pragma unroll
    for (int c = 0; c < NC; ++c) v[c] = fb[(size_t)c * FHW];
    f32x4* row = (f32x4*)(T + ((size_t)b * FHW + pix) * NC);
    #pragma unroll
    for (int r = 0; r < NC / 4; ++r) {
        f32x4 x = {v[4*r], v[4*r+1], v[4*r+2], v[4*r+3]};
        row[r] = x;
    }
}

// One thread per 4 z-consecutive voxels. Projection = PINNED R14 pipeline
// (f32, contract off, pairwise association, IEEE div, rndne) -- bit-exact.
// Gather from transposed T (8 float4 per valid voxel), 4x4 register
// transpose per channel-quad, f32x4 nontemporal stores (1KB/wave-inst).
__global__ __launch_bounds__(256) void voxel_backproject_kernel(
    const float* __restrict__ proj,
    const float* __restrict__ T,
    const float* __restrict__ origin,
    float* __restrict__ out)
{
#pragma clang fp contract(off)
    const int per_b = NVOX / 4;                       // 262144 threads per batch
    const int tid = blockIdx.x * 256 + threadIdx.x;
    const int b  = tid / per_b;
    const int v4 = tid - b * per_b;
    const int n0 = v4 * 4;
    const int i  = n0 >> 13;
    const int j  = (n0 >> 6) & (NY - 1);
    const int k0 = n0 & (NZ - 1);

    const float* P = proj + b * 12;
    const float ox = origin[b * 3 + 0];
    const float oy = origin[b * 3 + 1];
    const float oz = origin[b * 3 + 2];

    const float wx = (float)i * VOXSZ + ox;
    const float wy = (float)j * VOXSZ + oy;

    const float tx = P[0] * wx + P[1] * wy;
    const float ty = P[4] * wx + P[5] * wy;
    const float tz = P[8] * wx + P[9] * wy;

    bool vld[4];
    const f32x4* rowp[4];
    float vmp[4];

    #pragma unroll
    for (int q = 0; q < 4; ++q) {
        const float wz = (float)(k0 + q) * VOXSZ + oz;
        const float cx = tx + (P[2]  * wz + P[3]);
        const float cy = ty + (P[6]  * wz + P[7]);
        const float cz = tz + (P[10] * wz + P[11]);
        const float qx = cx / cz;
        const float qy = cy / cz;
        const int px = __float2int_rn(qx);
        const int py = __float2int_rn(qy);
        const bool v = (px >= 0) & (py >= 0) & (px < FW) & (py < FH) & (cz > 0.0f);
        vld[q] = v;
        vmp[q] = v ? 1.0f : 0.0f;
        const int idx = v ? (py * FW + px) : 0;
        rowp[q] = (const f32x4*)(T + ((size_t)b * FHW + idx) * NC);
    }

    float* ob = out + (size_t)b * NC * NVOX + n0;
    const bool any = vld[0] | vld[1] | vld[2] | vld[3];
    const f32x4 z4 = {0.0f, 0.0f, 0.0f, 0.0f};

    if (any) {
        #pragma unroll
        for (int r = 0; r < 8; ++r) {
            const f32x4 q0 = vld[0] ? rowp[0][r] : z4;
            const f32x4 q1 = vld[1] ? rowp[1][r] : z4;
            const f32x4 q2 = vld[2] ? rowp[2][r] : z4;
            const f32x4 q3 = vld[3] ? rowp[3][r] : z4;
            const f32x4 s0 = {q0.x, q1.x, q2.x, q3.x};
            const f32x4 s1 = {q0.y, q1.y, q2.y, q3.y};
            const f32x4 s2 = {q0.z, q1.z, q2.z, q3.z};
            const f32x4 s3 = {q0.w, q1.w, q2.w, q3.w};
            __builtin_nontemporal_store(s0, (f32x4*)(ob + (size_t)(4*r + 0) * NVOX));
            __builtin_nontemporal_store(s1, (f32x4*)(ob + (size_t)(4*r + 1) * NVOX));
            __builtin_nontemporal_store(s2, (f32x4*)(ob + (size_t)(4*r + 2) * NVOX));
            __builtin_nontemporal_store(s3, (f32x4*)(ob + (size_t)(4*r + 3) * NVOX));
        }
    } else {
        #pragma unroll
        for (int c = 0; c < NC; ++c)
            __builtin_nontemporal_store(z4, (f32x4*)(ob + (size_t)c * NVOX));
    }

    float* vout = out + (size_t)NB * NC * NVOX + (size_t)b * NVOX + n0;
    const f32x4 vm = {vmp[0], vmp[1], vmp[2], vmp[3]};
    __builtin_nontemporal_store(vm, (f32x4*)vout);
}

extern "C" void kernel_launch(void* const* d_in, const int* in_sizes, int n_in,
                              void* d_out, int out_size, void* d_ws, size_t ws_size,
                              hipStream_t stream) {
    const float* proj   = (const float*)d_in[0];
    const float* feat   = (const float*)d_in[1];
    const float* origin = (const float*)d_in[2];
    float* out = (float*)d_out;

    float* T = (float*)d_ws;
    transpose_feat_kernel<<<(NB * FHW) / 256, 256, 0, stream>>>(feat, T);
    const int total_threads = NB * (NVOX / 4);        // 524288
    voxel_backproject_kernel<<<total_threads / 256, 256, 0, stream>>>(proj, T, origin, out);
}

// Round 18
// 53.729 us; speedup vs baseline: 1.9161x; 1.9161x over previous
//
#include <hip/hip_runtime.h>
#include <math.h>

#define NX 128
#define NY 128
#define NZ 64
#define NVOX (NX * NY * NZ)   // 1048576 = 1<<20
#define NC 32
#define FH 120
#define FW 160
#define FHW (FH * FW)         // 19200
#define VOXSZ 0.04f
#define NB 2
#define T_BYTES ((size_t)NB * FHW * NC * 4)   // 4,915,200

// Transpose features (B,C,H*W) -> T (B, H*W, C).
__global__ __launch_bounds__(256) void transpose_feat_kernel(
    const float* __restrict__ feat, float* __restrict__ T)
{
    const int t = blockIdx.x * 256 + threadIdx.x;     // 0..38399
    const int b = t / FHW;
    const int pix = t - b * FHW;
    const float* fb = feat + (size_t)b * NC * FHW + pix;
    float v[NC];
    #pragma unroll
    for (int c = 0; c < NC; ++c) v[c] = fb[(size_t)c * FHW];
    float4* row = (float4*)(T + ((size_t)b * FHW + pix) * NC);
    #pragma unroll
    for (int r = 0; r < NC / 4; ++r)
        row[r] = make_float4(v[4*r], v[4*r+1], v[4*r+2], v[4*r+3]);
}

// One thread per voxel (R15 structure -- 2M threads, max latency hiding).
// Projection = PINNED R14 pipeline (f32, contract off, pairwise association,
// IEEE div, rndne) -- bit-exact vs harness reference.
// Stores: NORMAL cached stores (the 6.9 TB/s fill-kernel path), not NT.
__global__ __launch_bounds__(256) void voxel_backproject_kernel(
    const float* __restrict__ proj,
    const float* __restrict__ T,
    const float* __restrict__ origin,
    float* __restrict__ out)
{
#pragma clang fp contract(off)
    const int tid = blockIdx.x * 256 + threadIdx.x;
    const int b = tid >> 20;
    const int n = tid & (NVOX - 1);
    const int i = n >> 13;
    const int j = (n >> 6) & (NY - 1);
    const int k = n & (NZ - 1);

    const float* P = proj + b * 12;
    const float ox = origin[b * 3 + 0];
    const float oy = origin[b * 3 + 1];
    const float oz = origin[b * 3 + 2];

    const float wx = (float)i * VOXSZ + ox;
    const float wy = (float)j * VOXSZ + oy;
    const float wz = (float)k * VOXSZ + oz;

    const float tx = P[0] * wx + P[1] * wy;
    const float ty = P[4] * wx + P[5] * wy;
    const float tz = P[8] * wx + P[9] * wy;

    const float cx = tx + (P[2]  * wz + P[3]);
    const float cy = ty + (P[6]  * wz + P[7]);
    const float cz = tz + (P[10] * wz + P[11]);

    const float qx = cx / cz;
    const float qy = cy / cz;
    const int px = __float2int_rn(qx);
    const int py = __float2int_rn(qy);
    const bool v = (px >= 0) & (py >= 0) & (px < FW) & (py < FH) & (cz > 0.0f);

    float4 r0 = {0,0,0,0}, r1 = {0,0,0,0}, r2 = {0,0,0,0}, r3 = {0,0,0,0};
    float4 r4 = {0,0,0,0}, r5 = {0,0,0,0}, r6 = {0,0,0,0}, r7 = {0,0,0,0};
    if (v) {
        const int idx = py * FW + px;
        const float4* row = (const float4*)(T + ((size_t)b * FHW + idx) * NC);
        r0 = row[0]; r1 = row[1]; r2 = row[2]; r3 = row[3];
        r4 = row[4]; r5 = row[5]; r6 = row[6]; r7 = row[7];
    }

    float* ob = out + (size_t)b * NC * NVOX + n;
    const float4 rr[8] = {r0,r1,r2,r3,r4,r5,r6,r7};
    #pragma unroll
    for (int t = 0; t < 8; ++t) {
        ob[(size_t)(4*t + 0) * NVOX] = rr[t].x;
        ob[(size_t)(4*t + 1) * NVOX] = rr[t].y;
        ob[(size_t)(4*t + 2) * NVOX] = rr[t].z;
        ob[(size_t)(4*t + 3) * NVOX] = rr[t].w;
    }
    out[(size_t)NB * NC * NVOX + (size_t)b * NVOX + n] = v ? 1.0f : 0.0f;
}

extern "C" void kernel_launch(void* const* d_in, const int* in_sizes, int n_in,
                              void* d_out, int out_size, void* d_ws, size_t ws_size,
                              hipStream_t stream) {
    const float* proj   = (const float*)d_in[0];
    const float* feat   = (const float*)d_in[1];
    const float* origin = (const float*)d_in[2];
    float* out = (float*)d_out;

    float* T = (float*)d_ws;
    transpose_feat_kernel<<<(NB * FHW) / 256, 256, 0, stream>>>(feat, T);
    const int total = NB * NVOX;                      // 2097152
    voxel_backproject_kernel<<<total / 256, 256, 0, stream>>>(proj, T, origin, out);
}